// Round 8
// baseline (368.212 us; speedup 1.0000x reference)
//
#include <hip/hip_runtime.h>
#include <math.h>

#define D 64
#define CHUNK 128   // edges per wave in k_fused

typedef __fp16 fp16x2 __attribute__((ext_vector_type(2)));
typedef _Float16 half8 __attribute__((ext_vector_type(8)));
typedef __attribute__((ext_vector_type(4))) float f32x4;

union h8pun { half8 v; fp16x2 h2[4]; };

// Slot permutation pi2 (bakes the qT-MFMA C-layout -> logits A-layout handoff):
//   n -> slot = (t&1)*32 + q*8 + 2r + (t>>1)   with t=n>>4, q=(n>>2)&3, r=n&3
//   slot s -> n = 16*(((s&1)<<1)|(s>>5)) + 4*((s>>3)&3) + ((s>>1)&3)

// ---------------------------------------------------------------------------
// Projection + folded prep.
//  roles:  tid<=N: start[] binary search
//          next D*D: W2h[c][s] = fp16(W2[n(s)][c])       (pi2-permuted rows)
//          next D*D: W1ah[n][k] = fp16(W1[k][n])          (W1a^T, prepacked)
//  waves [0,wavesU):  u2e_h[r] = fp16(u2e[r])             (cvt copy only)
//  waves [wavesU,..): p[r] = pi2( u2e[nodes[r]] @ W1b + b1 )
__global__ __launch_bounds__(256) void k_proj(const float* __restrict__ u2e,
                                              const int* __restrict__ nodes,
                                              const float* __restrict__ W1,
                                              const float* __restrict__ b1,
                                              const float* __restrict__ W2,
                                              _Float16* __restrict__ W2h,
                                              _Float16* __restrict__ W1ah,
                                              const int* __restrict__ seg_ids,
                                              int* __restrict__ start,
                                              _Float16* __restrict__ u2e_h,
                                              _Float16* __restrict__ p,
                                              int U, int N, int E,
                                              int wavesU, int wavesN) {
    int tid = blockIdx.x * blockDim.x + (int)threadIdx.x;
    if (tid <= N) {
        int lo = 0, hi = E;
        while (lo < hi) {
            int mid = (lo + hi) >> 1;
            if (seg_ids[mid] < tid) lo = mid + 1; else hi = mid;
        }
        start[tid] = lo;
    } else if (tid <= N + D * D) {
        int j0 = tid - (N + 1);
        int c = j0 >> 6, s = j0 & 63;
        int n = 16 * (((s & 1) << 1) | (s >> 5)) + 4 * ((s >> 3) & 3) + ((s >> 1) & 3);
        W2h[c * D + s] = (_Float16)W2[n * D + c];
    } else if (tid <= N + 2 * D * D) {
        int j0 = tid - (N + 1 + D * D);
        int n = j0 >> 6, k = j0 & 63;
        W1ah[n * D + k] = (_Float16)W1[k * D + n];
    }

    int lane = threadIdx.x & 63;
    int m = lane & 15, quad = lane >> 4;
    int wave = (blockIdx.x * blockDim.x + threadIdx.x) >> 6;

    if (wave < wavesU) {
        // ---- u2e -> u2e_h cvt copy ----
        int ngroups = (U + 15) / 16;
        for (int g = wave; g < ngroups; g += wavesU) {
            int r_ = g * 16 + m;
            if (r_ >= U) continue;
            const float4* arow = (const float4*)(u2e + (size_t)r_ * D);
            float4 x0 = arow[quad * 2], x1 = arow[quad * 2 + 1];
            float4 y0 = arow[8 + quad * 2], y1 = arow[8 + quad * 2 + 1];
            h8pun A0, A1;
            A0.h2[0] = __builtin_amdgcn_cvt_pkrtz(x0.x, x0.y);
            A0.h2[1] = __builtin_amdgcn_cvt_pkrtz(x0.z, x0.w);
            A0.h2[2] = __builtin_amdgcn_cvt_pkrtz(x1.x, x1.y);
            A0.h2[3] = __builtin_amdgcn_cvt_pkrtz(x1.z, x1.w);
            A1.h2[0] = __builtin_amdgcn_cvt_pkrtz(y0.x, y0.y);
            A1.h2[1] = __builtin_amdgcn_cvt_pkrtz(y0.z, y0.w);
            A1.h2[2] = __builtin_amdgcn_cvt_pkrtz(y1.x, y1.y);
            A1.h2[3] = __builtin_amdgcn_cvt_pkrtz(y1.z, y1.w);
            *(half8*)(u2e_h + (size_t)r_ * D + quad * 8) = A0.v;
            *(half8*)(u2e_h + (size_t)r_ * D + 32 + quad * 8) = A1.v;
        }
        return;
    }

    // ---- p-side MFMA projection, stored in pi2 slot layout ----
    int w0 = wave - wavesU;
    half8 Bf[2][4];
    float bv[4];
#pragma unroll
    for (int t = 0; t < 4; ++t) {
        int n = m + 16 * t;
        bv[t] = b1[n];
#pragma unroll
        for (int kh = 0; kh < 2; ++kh) {
            int k0 = D + kh * 32 + quad * 8;   // W1b rows
#pragma unroll
            for (int j = 0; j < 8; ++j) Bf[kh][t][j] = (_Float16)W1[(size_t)(k0 + j) * D + n];
        }
    }
    int ngroups = (N + 15) / 16;
    for (int g = w0; g < ngroups; g += wavesN) {
        int r_ = g * 16 + m;
        int rs = r_ < N ? r_ : N - 1;
        int src = nodes[rs];
        const float4* arow = (const float4*)(u2e + (size_t)src * D);
        float4 x0 = arow[quad * 2], x1 = arow[quad * 2 + 1];
        float4 y0 = arow[8 + quad * 2], y1 = arow[8 + quad * 2 + 1];
        h8pun A0, A1;
        A0.h2[0] = __builtin_amdgcn_cvt_pkrtz(x0.x, x0.y);
        A0.h2[1] = __builtin_amdgcn_cvt_pkrtz(x0.z, x0.w);
        A0.h2[2] = __builtin_amdgcn_cvt_pkrtz(x1.x, x1.y);
        A0.h2[3] = __builtin_amdgcn_cvt_pkrtz(x1.z, x1.w);
        A1.h2[0] = __builtin_amdgcn_cvt_pkrtz(y0.x, y0.y);
        A1.h2[1] = __builtin_amdgcn_cvt_pkrtz(y0.z, y0.w);
        A1.h2[2] = __builtin_amdgcn_cvt_pkrtz(y1.x, y1.y);
        A1.h2[3] = __builtin_amdgcn_cvt_pkrtz(y1.z, y1.w);
        f32x4 C[4];
#pragma unroll
        for (int t = 0; t < 4; ++t) C[t] = (f32x4){bv[t], bv[t], bv[t], bv[t]};
#pragma unroll
        for (int t = 0; t < 4; ++t) {
            C[t] = __builtin_amdgcn_mfma_f32_16x16x32_f16(A0.v, Bf[0][t], C[t], 0, 0, 0);
            C[t] = __builtin_amdgcn_mfma_f32_16x16x32_f16(A1.v, Bf[1][t], C[t], 0, 0, 0);
        }
        // pi2 store: value for col n=m+16t' goes to slot (t'&1)*32 + (m>>2)*8 + 2*(m&3) + (t'>>1)
        int qq = m >> 2, rr = m & 3;
#pragma unroll
        for (int r = 0; r < 4; ++r) {
            int row = g * 16 + quad * 4 + r;
            if (row < N) {
                fp16x2 v0, v1;
                v0[0] = (_Float16)C[0][r]; v0[1] = (_Float16)C[2][r];
                v1[0] = (_Float16)C[1][r]; v1[1] = (_Float16)C[3][r];
                *(fp16x2*)(p + (size_t)row * D + qq * 8 + rr * 2) = v0;
                *(fp16x2*)(p + (size_t)row * D + 32 + qq * 8 + rr * 2) = v1;
            }
        }
    }
}

// ---------------------------------------------------------------------------
// Fused edge+aggregation, register-only (NO LDS).  One wave per node-aligned
// ~CHUNK edge range (no atomics, no stitch).  Per 16-edge set:
//  1. gather u2e_h[nbr] (the only random gather) -- lane m holds edge m's row
//     slices at quad*8: this is ALREADY a B-fragment of u^T.
//  2. swapped q-MFMA: Cq[ta] = W1a^T-frag x u^T  -> q lands EDGE-ON-M:
//     lane (m,quad) reg (ta,r) = q[edge m][n=16ta+4quad+r].
//  3. x = relu(q + p) relabeled via pi2 directly into logits A-frags (pure
//     register indexing; W2h rows pre-permuted by pi2 to compensate).
//  4. logits MFMA -> m-butterfly -> ex = exp(l+b3) redistributed to edge-on-m.
//  5. segmented accumulate reusing the SAME u-row registers; flush per node
//     boundary via m-butterfly + direct normalized store.
__global__ __launch_bounds__(256, 3) void k_fused(const int* __restrict__ neigh_idx,
                                                  const int* __restrict__ seg_ids,
                                                  const _Float16* __restrict__ u2e_h,
                                                  const _Float16* __restrict__ p,
                                                  const _Float16* __restrict__ W2h,
                                                  const _Float16* __restrict__ W1ah,
                                                  const float* __restrict__ b2,
                                                  const float* __restrict__ w3,
                                                  const float* __restrict__ b3,
                                                  const int* __restrict__ start,
                                                  const int* __restrict__ nodes,
                                                  const float* __restrict__ u2e,
                                                  float* __restrict__ out,
                                                  int E, int N, int nchunks) {
    int tid = blockIdx.x * blockDim.x + (int)threadIdx.x;
    // zero-neighbor fallback (degree-0 nodes never appear in seg_ids)
    if (tid < N && start[tid + 1] == start[tid]) {
        const float4* src = (const float4*)(u2e + (size_t)nodes[tid] * D);
        float4* dst = (float4*)(out + (size_t)tid * D);
#pragma unroll
        for (int j = 0; j < 16; ++j) dst[j] = src[j];
    }

    int lane = threadIdx.x & 63;
    int m = lane & 15, quad = lane >> 4;
    int wave = tid >> 6;
    if (wave >= nchunks) return;
    int e_lo = wave * CHUNK;

    // node-aligned edge range: nodes n with start[n] in [e_lo, e_lo+CHUNK)
    int lo = 0, hi = N + 1;
    while (lo < hi) { int mid = (lo + hi) >> 1; if (start[mid] < e_lo) lo = mid + 1; else hi = mid; }
    int s_begin = (lo <= N) ? start[lo] : E;
    int bound = e_lo + CHUNK;
    hi = N + 1;
    while (lo < hi) { int mid = (lo + hi) >> 1; if (start[mid] < bound) lo = mid + 1; else hi = mid; }
    int s_end = (lo <= N) ? start[lo] : E;
    if (s_begin >= s_end) return;

    // weight fragments (all prepacked fp16 tables, half8 loads)
    half8 Bf1[2][4], Bf2[2][4];
    float b2v[4], w3v[4];
#pragma unroll
    for (int t = 0; t < 4; ++t) {
        int n = m + 16 * t;
        b2v[t] = b2[n];
        w3v[t] = w3[n];
        Bf2[0][t] = *(const half8*)(W2h + n * D + quad * 8);
        Bf2[1][t] = *(const half8*)(W2h + n * D + 32 + quad * 8);
        int na = 16 * t + m;   // A-frag row m of block t  ->  n = 16t+m
        Bf1[0][t] = *(const half8*)(W1ah + na * D + quad * 8);
        Bf1[1][t] = *(const half8*)(W1ah + na * D + 32 + quad * 8);
    }
    float b3v = b3[0];

    // pipeline: idx 2 sets ahead, rows 1 set ahead
    int ecA = s_begin + m; if (ecA > s_end - 1) ecA = s_end - 1;
    int nbA = neigh_idx[ecA], sgA = seg_ids[ecA];
    int nbB = nbA, sgB = sgA;
    if (s_begin + 16 < s_end) {
        int ecB = s_begin + 16 + m; if (ecB > s_end - 1) ecB = s_end - 1;
        nbB = neigh_idx[ecB]; sgB = seg_ids[ecB];
    }
    const half8* ur = (const half8*)(u2e_h + (size_t)nbA * D);
    half8 ua0 = ur[quad], ua1 = ur[quad + 4];
    const half8* pr = (const half8*)(p + (size_t)sgA * D);
    half8 pa0 = pr[quad], pa1 = pr[quad + 4];

    float acc0[8], acc1[8], dsum = 0.0f;
    bool dirty = false;
    int cur_seg = seg_ids[s_begin];
#pragma unroll
    for (int j = 0; j < 8; ++j) { acc0[j] = 0.0f; acc1[j] = 0.0f; }

    auto flush = [&]() {
#pragma unroll
        for (int off = 1; off <= 8; off <<= 1) {
#pragma unroll
            for (int j = 0; j < 8; ++j) {
                acc0[j] += __shfl_xor(acc0[j], off, 64);
                acc1[j] += __shfl_xor(acc1[j], off, 64);
            }
            dsum += __shfl_xor(dsum, off, 64);
        }
        if (m == 0) {
            float inv = 1.0f / dsum;
            float* o = out + (size_t)cur_seg * D + quad * 8;
            *(float4*)o = make_float4(acc0[0] * inv, acc0[1] * inv, acc0[2] * inv, acc0[3] * inv);
            *(float4*)(o + 4) = make_float4(acc0[4] * inv, acc0[5] * inv, acc0[6] * inv, acc0[7] * inv);
            float* o2 = o + 32;
            *(float4*)o2 = make_float4(acc1[0] * inv, acc1[1] * inv, acc1[2] * inv, acc1[3] * inv);
            *(float4*)(o2 + 4) = make_float4(acc1[4] * inv, acc1[5] * inv, acc1[6] * inv, acc1[7] * inv);
        }
#pragma unroll
        for (int j = 0; j < 8; ++j) { acc0[j] = 0.0f; acc1[j] = 0.0f; }
        dsum = 0.0f;
        dirty = false;
    };

    for (int e0 = s_begin; e0 < s_end; e0 += 16) {
        int sg_c = sgA;
        half8 cu0 = ua0, cu1 = ua1, cp0 = pa0, cp1 = pa1;
        bool valid = (e0 + m) < s_end;
        // rotate pipeline: idx for set+2, rows for set+1
        nbA = nbB; sgA = sgB;
        int e2 = e0 + 32;
        if (e2 < s_end) {
            int ec = e2 + m; if (ec > s_end - 1) ec = s_end - 1;
            nbB = neigh_idx[ec]; sgB = seg_ids[ec];
        }
        if (e0 + 16 < s_end) {
            const half8* ur2 = (const half8*)(u2e_h + (size_t)nbA * D);
            ua0 = ur2[quad]; ua1 = ur2[quad + 4];
            const half8* pr2 = (const half8*)(p + (size_t)sgA * D);
            pa0 = pr2[quad]; pa1 = pr2[quad + 4];
        }
        // swapped q-MFMA: edge lands on m
        f32x4 Cq[4];
#pragma unroll
        for (int t = 0; t < 4; ++t) Cq[t] = (f32x4){0.0f, 0.0f, 0.0f, 0.0f};
#pragma unroll
        for (int t = 0; t < 4; ++t) {
            Cq[t] = __builtin_amdgcn_mfma_f32_16x16x32_f16(Bf1[0][t], cu0, Cq[t], 0, 0, 0);
            Cq[t] = __builtin_amdgcn_mfma_f32_16x16x32_f16(Bf1[1][t], cu1, Cq[t], 0, 0, 0);
        }
        // x = relu(q + p) in pi2 slot layout -> logits A-frags (register-only)
        half8 xa0, xa1;
#pragma unroll
        for (int j = 0; j < 8; ++j) {
            xa0[j] = (_Float16)fmaxf(Cq[(j & 1) * 2][j >> 1] + (float)cp0[j], 0.0f);
            xa1[j] = (_Float16)fmaxf(Cq[(j & 1) * 2 + 1][j >> 1] + (float)cp1[j], 0.0f);
        }
        // logits MFMA (W2h pi2-compensated); output edge on (quad,r) as before
        f32x4 Cl[4];
#pragma unroll
        for (int t = 0; t < 4; ++t) Cl[t] = (f32x4){b2v[t], b2v[t], b2v[t], b2v[t]};
#pragma unroll
        for (int t = 0; t < 4; ++t) {
            Cl[t] = __builtin_amdgcn_mfma_f32_16x16x32_f16(xa0, Bf2[0][t], Cl[t], 0, 0, 0);
            Cl[t] = __builtin_amdgcn_mfma_f32_16x16x32_f16(xa1, Bf2[1][t], Cl[t], 0, 0, 0);
        }
        float pl[4];
#pragma unroll
        for (int r = 0; r < 4; ++r) {
            float s = 0.0f;
#pragma unroll
            for (int t = 0; t < 4; ++t) s += fmaxf(Cl[t][r], 0.0f) * w3v[t];
            pl[r] = s;
        }
#pragma unroll
        for (int off = 1; off <= 8; off <<= 1) {
#pragma unroll
            for (int r = 0; r < 4; ++r) pl[r] += __shfl_xor(pl[r], off, 64);
        }
        // redistribute: lane (m,quad) gets ex of its OWN edge (e0+m)
        int srcl = (m >> 2) << 4;
        float t0 = __shfl(pl[0], srcl, 64), t1 = __shfl(pl[1], srcl, 64);
        float t2 = __shfl(pl[2], srcl, 64), t3 = __shfl(pl[3], srcl, 64);
        int rr = m & 3;
        float lg = rr == 0 ? t0 : rr == 1 ? t1 : rr == 2 ? t2 : t3;
        float exm = __expf(lg + b3v);
        // segmented accumulate reusing the gathered row (sorted segs)
        int sgw = valid ? sg_c : 0x7fffffff;
        bool active = valid;
        while (__any(active)) {
            int s0 = active ? sgw : 0x7fffffff;
#pragma unroll
            for (int off = 1; off <= 8; off <<= 1) s0 = min(s0, __shfl_xor(s0, off, 64));
            if (s0 != cur_seg) { if (dirty) flush(); cur_seg = s0; }
            bool mine = active && (sgw == s0);
            float w = mine ? exm : 0.0f;
            dsum += w;
#pragma unroll
            for (int j = 0; j < 8; ++j) {
                acc0[j] += w * (float)cu0[j];
                acc1[j] += w * (float)cu1[j];
            }
            dirty = true;
            active = active && !mine;
        }
    }
    if (dirty) flush();
}

// ---------------------------------------------------------------------------
extern "C" void kernel_launch(void* const* d_in, const int* in_sizes, int n_in,
                              void* d_out, int out_size, void* d_ws, size_t ws_size,
                              hipStream_t stream) {
    const int* nodes = (const int*)d_in[0];
    const int* neigh_idx = (const int*)d_in[1];
    const int* seg_ids = (const int*)d_in[2];
    const float* u2e = (const float*)d_in[3];
    const float* W1 = (const float*)d_in[4];
    const float* b1 = (const float*)d_in[5];
    const float* W2 = (const float*)d_in[6];
    const float* b2 = (const float*)d_in[7];
    const float* w3 = (const float*)d_in[8];
    const float* b3 = (const float*)d_in[9];
    float* out = (float*)d_out;

    int N = in_sizes[0];
    int E = in_sizes[1];
    int U = in_sizes[3] / D;

    int nchunks = (E + CHUNK - 1) / CHUNK;

    char* ws = (char*)d_ws;
    size_t off = 0;
    auto alloc = [&](size_t bytes) {
        void* ptr = ws + off;
        off = (off + bytes + 255) & ~(size_t)255;
        return ptr;
    };
    int* start = (int*)alloc((size_t)(N + 1) * 4);
    _Float16* W2h = (_Float16*)alloc((size_t)D * D * 2);
    _Float16* W1ah = (_Float16*)alloc((size_t)D * D * 2);
    _Float16* p = (_Float16*)alloc((size_t)N * D * 2);
    _Float16* u2e_h = (_Float16*)alloc((size_t)U * D * 2);
    (void)ws_size;

    const int wavesU = 6144, wavesN = 2048;
    k_proj<<<(wavesU + wavesN) / 4, 256, 0, stream>>>(u2e, nodes, W1, b1, W2, W2h, W1ah,
                                                      seg_ids, start, u2e_h, p,
                                                      U, N, E, wavesU, wavesN);
    k_fused<<<(nchunks + 3) / 4, 256, 0, stream>>>(neigh_idx, seg_ids, u2e_h, p,
                                                   W2h, W1ah, b2, w3, b3, start,
                                                   nodes, u2e, out, E, N, nchunks);
}

// Round 9
// 209.422 us; speedup vs baseline: 1.7582x; 1.7582x over previous
//
#include <hip/hip_runtime.h>
#include <math.h>

#define D 64

typedef __fp16 fp16x2 __attribute__((ext_vector_type(2)));
typedef _Float16 half8 __attribute__((ext_vector_type(8)));
typedef _Float16 half4v __attribute__((ext_vector_type(4)));
typedef __attribute__((ext_vector_type(4))) float f32x4;

union h8pun { half8 v; fp16x2 h2[4]; };

// ---------------------------------------------------------------------------
// Combined MFMA row-projection (fp16), both passes in one launch, PLUS the
// former k_prep roles folded in as predicated thread-work:
//   - tid <= N:                start[tid] via binary search on sorted seg_ids
//   - tid in (N, N+D*D]:       W2h[n][pos] = fp16(W2[pi_inv(pos)][n])
// W1 staging gone: each wave transposes W1 on the fly (W1 is 32 KB, L2-hot).
// Waves [0, wavesU):     q~[r] = pi(u2e[r] @ W1a), u2e_h[r] = fp16(u2e[r])
// Waves [wavesU, ...):   p~[r] = pi(u2e[nodes[r]] @ W1b + b1)
// pi-layout store: lane writes one contiguous half4 per row (coalesced 128 B).
__global__ __launch_bounds__(256) void k_proj_both(const float* __restrict__ u2e,
                                                   const int* __restrict__ nodes,
                                                   const float* __restrict__ W1,
                                                   const float* __restrict__ b1,
                                                   const float* __restrict__ W2,
                                                   _Float16* __restrict__ W2h,
                                                   const int* __restrict__ seg_ids,
                                                   int* __restrict__ start,
                                                   _Float16* __restrict__ q,
                                                   _Float16* __restrict__ u2e_h,
                                                   _Float16* __restrict__ p,
                                                   int U, int N, int E,
                                                   int wavesU, int wavesN) {
    // ---- folded prep roles ----
    int tid = blockIdx.x * blockDim.x + (int)threadIdx.x;
    if (tid <= N) {
        int lo = 0, hi = E;
        while (lo < hi) {
            int mid = (lo + hi) >> 1;
            if (seg_ids[mid] < tid) lo = mid + 1; else hi = mid;
        }
        start[tid] = lo;
    } else if (tid <= N + D * D) {
        int j = tid - (N + 1);
        int n = j >> 6, pos = j & 63;
        int k = (pos >> 2) + 16 * (pos & 3);   // pi_inv
        W2h[n * D + pos] = (_Float16)W2[k * D + n];
    }

    int lane = threadIdx.x & 63;
    int m = lane & 15, quad = lane >> 4;
    int wave = (blockIdx.x * blockDim.x + threadIdx.x) >> 6;

    const int* idx;
    const float* bias;
    _Float16* outp;
    _Float16* copyp;
    int R, w0, wstride, w1off;
    if (wave < wavesU) {
        idx = nullptr; bias = nullptr; outp = q; copyp = u2e_h;
        R = U; w0 = wave; wstride = wavesU; w1off = 0;
    } else {
        idx = nodes; bias = b1; outp = p; copyp = nullptr;
        R = N; w0 = wave - wavesU; wstride = wavesN; w1off = D;
    }

    // on-the-fly transpose: Bf[kh][t][j] = W1[(w1off + kh*32+quad*8+j)*D + n]
    half8 Bf[2][4];
    float bv[4];
#pragma unroll
    for (int t = 0; t < 4; ++t) {
        int n = m + 16 * t;
        bv[t] = bias ? bias[n] : 0.0f;
#pragma unroll
        for (int kh = 0; kh < 2; ++kh) {
            int k0 = w1off + kh * 32 + quad * 8;
#pragma unroll
            for (int j = 0; j < 8; ++j) Bf[kh][t][j] = (_Float16)W1[(size_t)(k0 + j) * D + n];
        }
    }

    int ngroups = (R + 15) / 16;
    for (int g = w0; g < ngroups; g += wstride) {
        int r_ = g * 16 + m;
        int rs = r_ < R ? r_ : R - 1;
        int src = idx ? idx[rs] : rs;
        const float4* arow = (const float4*)(u2e + (size_t)src * D);
        float4 x0 = arow[quad * 2], x1 = arow[quad * 2 + 1];
        float4 y0 = arow[8 + quad * 2], y1 = arow[8 + quad * 2 + 1];
        h8pun A0, A1;
        A0.h2[0] = __builtin_amdgcn_cvt_pkrtz(x0.x, x0.y);
        A0.h2[1] = __builtin_amdgcn_cvt_pkrtz(x0.z, x0.w);
        A0.h2[2] = __builtin_amdgcn_cvt_pkrtz(x1.x, x1.y);
        A0.h2[3] = __builtin_amdgcn_cvt_pkrtz(x1.z, x1.w);
        A1.h2[0] = __builtin_amdgcn_cvt_pkrtz(y0.x, y0.y);
        A1.h2[1] = __builtin_amdgcn_cvt_pkrtz(y0.z, y0.w);
        A1.h2[2] = __builtin_amdgcn_cvt_pkrtz(y1.x, y1.y);
        A1.h2[3] = __builtin_amdgcn_cvt_pkrtz(y1.z, y1.w);
        if (copyp && r_ < R) {
            *(half8*)(copyp + (size_t)r_ * D + quad * 8) = A0.v;
            *(half8*)(copyp + (size_t)r_ * D + 32 + quad * 8) = A1.v;
        }
        f32x4 C[4];
#pragma unroll
        for (int t = 0; t < 4; ++t) C[t] = (f32x4){bv[t], bv[t], bv[t], bv[t]};
#pragma unroll
        for (int t = 0; t < 4; ++t) {
            C[t] = __builtin_amdgcn_mfma_f32_16x16x32_f16(A0.v, Bf[0][t], C[t], 0, 0, 0);
            C[t] = __builtin_amdgcn_mfma_f32_16x16x32_f16(A1.v, Bf[1][t], C[t], 0, 0, 0);
        }
        // pi-layout store: position m*4+t holds col m+16t -> one half4 per row.
#pragma unroll
        for (int r = 0; r < 4; ++r) {
            int row = g * 16 + quad * 4 + r;
            if (row < R) {
                half4v hv = {(_Float16)C[0][r], (_Float16)C[1][r],
                             (_Float16)C[2][r], (_Float16)C[3][r]};
                *(half4v*)(outp + (size_t)row * D + m * 4) = hv;
            }
        }
    }
}

// ---------------------------------------------------------------------------
// Edge kernel: logits via fp16 MFMA, 32 edges per wave-iteration, storing
// ex = exp(logit + b3) (softmax shift-invariance; validated).
// Pipeline: indices prefetched TWO grid-stride iterations ahead, q/p rows
// prefetched ONE iteration ahead -- the row gathers for iter g+1 are in
// flight during the MFMA/reduce/store of iter g.
__global__ __launch_bounds__(256) void k_edge_ex(const int* __restrict__ neigh_idx,
                                                 const int* __restrict__ seg_ids,
                                                 const _Float16* __restrict__ q,
                                                 const _Float16* __restrict__ p,
                                                 const _Float16* __restrict__ W2h,
                                                 const float* __restrict__ b2,
                                                 const float* __restrict__ w3,
                                                 const float* __restrict__ b3,
                                                 float* __restrict__ exb, int E) {
    int lane = threadIdx.x & 63;
    int m = lane & 15, quad = lane >> 4;

    half8 Bf[2][4];
    float b2v[4], w3v[4];
#pragma unroll
    for (int t = 0; t < 4; ++t) {
        int n = m + 16 * t;
        b2v[t] = b2[n];
        w3v[t] = w3[n];
        Bf[0][t] = *(const half8*)(W2h + n * D + quad * 8);
        Bf[1][t] = *(const half8*)(W2h + n * D + 32 + quad * 8);
    }
    float b3v = b3[0];
    const half8 hz = {0, 0, 0, 0, 0, 0, 0, 0};

    int ngroups = (E + 31) / 32;
    int wave = (blockIdx.x * blockDim.x + threadIdx.x) >> 6;
    int nwaves = (gridDim.x * blockDim.x) >> 6;

    // idxA = indices for the CURRENT iteration, idxB = next iteration
    int nbra = 0, sega = 0, nbrb = 0, segb = 0;
    int nbra2 = 0, sega2 = 0, nbrb2 = 0, segb2 = 0;
    if (wave < ngroups) {
        int ea = wave * 32 + m, eb = ea + 16;
        int eas = ea < E ? ea : E - 1;
        int ebs = eb < E ? eb : E - 1;
        nbra = neigh_idx[eas]; sega = seg_ids[eas];
        nbrb = neigh_idx[ebs]; segb = seg_ids[ebs];
    }
    if (wave + nwaves < ngroups) {
        int ea = (wave + nwaves) * 32 + m, eb = ea + 16;
        int eas = ea < E ? ea : E - 1;
        int ebs = eb < E ? eb : E - 1;
        nbra2 = neigh_idx[eas]; sega2 = seg_ids[eas];
        nbrb2 = neigh_idx[ebs]; segb2 = seg_ids[ebs];
    }
    // current rows
    half8 qa0 = {0}, qa1 = {0}, pa0 = {0}, pa1 = {0};
    half8 qb0 = {0}, qb1 = {0}, pb0 = {0}, pb1 = {0};
    if (wave < ngroups) {
        const half8* qra = (const half8*)(q + (size_t)nbra * D);
        const half8* pra = (const half8*)(p + (size_t)sega * D);
        const half8* qrb = (const half8*)(q + (size_t)nbrb * D);
        const half8* prb = (const half8*)(p + (size_t)segb * D);
        qa0 = qra[quad]; qa1 = qra[quad + 4];
        pa0 = pra[quad]; pa1 = pra[quad + 4];
        qb0 = qrb[quad]; qb1 = qrb[quad + 4];
        pb0 = prb[quad]; pb1 = prb[quad + 4];
    }

    for (int g = wave; g < ngroups; g += nwaves) {
        // snapshot current rows
        half8 cqa0 = qa0, cqa1 = qa1, cpa0 = pa0, cpa1 = pa1;
        half8 cqb0 = qb0, cqb1 = qb1, cpb0 = pb0, cpb1 = pb1;
        // rotate idx: current <- next; issue idx loads for g+2*nwaves
        nbra = nbra2; sega = sega2; nbrb = nbrb2; segb = segb2;
        int g2 = g + 2 * nwaves;
        if (g2 < ngroups) {
            int ea = g2 * 32 + m, eb = ea + 16;
            int eas = ea < E ? ea : E - 1;
            int ebs = eb < E ? eb : E - 1;
            nbra2 = neigh_idx[eas]; sega2 = seg_ids[eas];
            nbrb2 = neigh_idx[ebs]; segb2 = seg_ids[ebs];
        }
        // issue next iteration's row gathers (in flight during compute below)
        if (g + nwaves < ngroups) {
            const half8* qra = (const half8*)(q + (size_t)nbra * D);
            const half8* pra = (const half8*)(p + (size_t)sega * D);
            const half8* qrb = (const half8*)(q + (size_t)nbrb * D);
            const half8* prb = (const half8*)(p + (size_t)segb * D);
            qa0 = qra[quad]; qa1 = qra[quad + 4];
            pa0 = pra[quad]; pa1 = pra[quad + 4];
            qb0 = qrb[quad]; qb1 = qrb[quad + 4];
            pb0 = prb[quad]; pb1 = prb[quad + 4];
        }
        // ---- compute with current rows ----
        half8 Aa0 = __builtin_elementwise_max(cqa0 + cpa0, hz);
        half8 Aa1 = __builtin_elementwise_max(cqa1 + cpa1, hz);
        half8 Ab0 = __builtin_elementwise_max(cqb0 + cpb0, hz);
        half8 Ab1 = __builtin_elementwise_max(cqb1 + cpb1, hz);
        f32x4 Ca[4], Cb[4];
#pragma unroll
        for (int t = 0; t < 4; ++t) {
            Ca[t] = (f32x4){b2v[t], b2v[t], b2v[t], b2v[t]};
            Cb[t] = Ca[t];
        }
#pragma unroll
        for (int t = 0; t < 4; ++t) {
            Ca[t] = __builtin_amdgcn_mfma_f32_16x16x32_f16(Aa0, Bf[0][t], Ca[t], 0, 0, 0);
            Ca[t] = __builtin_amdgcn_mfma_f32_16x16x32_f16(Aa1, Bf[1][t], Ca[t], 0, 0, 0);
            Cb[t] = __builtin_amdgcn_mfma_f32_16x16x32_f16(Ab0, Bf[0][t], Cb[t], 0, 0, 0);
            Cb[t] = __builtin_amdgcn_mfma_f32_16x16x32_f16(Ab1, Bf[1][t], Cb[t], 0, 0, 0);
        }
        float pa[4], pb[4];
#pragma unroll
        for (int r = 0; r < 4; ++r) {
            float sa = 0.0f, sb = 0.0f;
#pragma unroll
            for (int t = 0; t < 4; ++t) {
                sa += fmaxf(Ca[t][r], 0.0f) * w3v[t];
                sb += fmaxf(Cb[t][r], 0.0f) * w3v[t];
            }
            pa[r] = sa; pb[r] = sb;
        }
#pragma unroll
        for (int off = 1; off <= 8; off <<= 1) {
#pragma unroll
            for (int r = 0; r < 4; ++r) {
                pa[r] += __shfl_xor(pa[r], off, 64);
                pb[r] += __shfl_xor(pb[r], off, 64);
            }
        }
        // ex = exp(logit + b3); store 4+4 contiguous edges from each quad's m==0 lane
        if (m == 0) {
            int e0 = g * 32 + quad * 4;
            if (e0 + 3 < E)
                *(float4*)(exb + e0) = make_float4(__expf(pa[0] + b3v), __expf(pa[1] + b3v),
                                                   __expf(pa[2] + b3v), __expf(pa[3] + b3v));
            else
#pragma unroll
                for (int r = 0; r < 4; ++r)
                    if (e0 + r < E) exb[e0 + r] = __expf(pa[r] + b3v);
            int e1 = e0 + 16;
            if (e1 + 3 < E)
                *(float4*)(exb + e1) = make_float4(__expf(pb[0] + b3v), __expf(pb[1] + b3v),
                                                   __expf(pb[2] + b3v), __expf(pb[3] + b3v));
            else
#pragma unroll
                for (int r = 0; r < 4; ++r)
                    if (e1 + r < E) exb[e1 + r] = __expf(pb[r] + b3v);
        }
    }
}

// ---------------------------------------------------------------------------
// Wave per node: single gather-accumulate pass.  The softmax denominator is
// accumulated IN-REGISTER alongside acc[] (dsum += w), reduced by the same
// butterfly, and applied as 1/dsum at the store -- no extra pass, no atomics.
// 8 lane-groups x 4-deep unroll = 32 neighbor rows in flight per wave.
__global__ __launch_bounds__(256) void k_agg_fast(const int* __restrict__ nodes,
                                                  const int* __restrict__ neigh_idx,
                                                  const float* __restrict__ u2e,
                                                  const _Float16* __restrict__ u2e_h,
                                                  const float* __restrict__ exb,
                                                  const int* __restrict__ start,
                                                  float* __restrict__ out, int N) {
    int n = blockIdx.x * 4 + ((int)threadIdx.x >> 6);
    int lane = threadIdx.x & 63;
    if (n >= N) return;
    int s = start[n];
    int t = start[n + 1];
    if (s == t) {  // no neighbors: own embedding (fp32, exact)
        int node = nodes[n];
        out[(size_t)n * D + lane] = u2e[(size_t)node * D + lane];
        return;
    }

    int grp = lane >> 3, sub = lane & 7;   // 8 groups of 8 lanes
    float acc[8];
#pragma unroll
    for (int j = 0; j < 8; ++j) acc[j] = 0.0f;
    float dsum = 0.0f;
    for (int i = s; i < t; i += 32) {
#pragma unroll
        for (int uu = 0; uu < 4; ++uu) {
            int ii = i + uu * 8 + grp;
            bool v = ii < t;
            int is = v ? ii : s;
            float w = exb[is];
            int nb = neigh_idx[is];
            half8 r = *(const half8*)(u2e_h + (size_t)nb * D + sub * 8);
            if (!v) w = 0.0f;
            dsum += w;
#pragma unroll
            for (int j = 0; j < 8; ++j) acc[j] += w * (float)r[j];
        }
    }
#pragma unroll
    for (int off = 8; off <= 32; off <<= 1) {
#pragma unroll
        for (int j = 0; j < 8; ++j) acc[j] += __shfl_xor(acc[j], off, 64);
        dsum += __shfl_xor(dsum, off, 64);
    }
    if (grp == 0) {
        float inv = 1.0f / dsum;
        float* o = out + (size_t)n * D + sub * 8;
        *(float4*)o = make_float4(acc[0] * inv, acc[1] * inv, acc[2] * inv, acc[3] * inv);
        *(float4*)(o + 4) = make_float4(acc[4] * inv, acc[5] * inv, acc[6] * inv, acc[7] * inv);
    }
}

// ---------------------------------------------------------------------------
extern "C" void kernel_launch(void* const* d_in, const int* in_sizes, int n_in,
                              void* d_out, int out_size, void* d_ws, size_t ws_size,
                              hipStream_t stream) {
    const int* nodes = (const int*)d_in[0];
    const int* neigh_idx = (const int*)d_in[1];
    const int* seg_ids = (const int*)d_in[2];
    const float* u2e = (const float*)d_in[3];
    const float* W1 = (const float*)d_in[4];
    const float* b1 = (const float*)d_in[5];
    const float* W2 = (const float*)d_in[6];
    const float* b2 = (const float*)d_in[7];
    const float* w3 = (const float*)d_in[8];
    const float* b3 = (const float*)d_in[9];
    float* out = (float*)d_out;

    int N = in_sizes[0];
    int E = in_sizes[1];
    int U = in_sizes[3] / D;

    char* ws = (char*)d_ws;
    size_t off = 0;
    auto alloc = [&](size_t bytes) {
        void* ptr = ws + off;
        off = (off + bytes + 255) & ~(size_t)255;
        return ptr;
    };
    float* exb = (float*)alloc((size_t)E * 4);
    int* start = (int*)alloc((size_t)(N + 1) * 4);
    _Float16* W2h = (_Float16*)alloc((size_t)D * D * 2);
    _Float16* q = (_Float16*)alloc((size_t)U * D * 2);
    _Float16* p = (_Float16*)alloc((size_t)N * D * 2);
    _Float16* u2e_h = (_Float16*)alloc((size_t)U * D * 2);
    (void)ws_size;

    const int wavesU = 6144, wavesN = 2048;
    k_proj_both<<<(wavesU + wavesN) / 4, 256, 0, stream>>>(u2e, nodes, W1, b1, W2, W2h,
                                                           seg_ids, start, q, u2e_h, p,
                                                           U, N, E, wavesU, wavesN);
    k_edge_ex<<<2048, 256, 0, stream>>>(neigh_idx, seg_ids, q, p, W2h,
                                        b2, w3, b3, exb, E);
    k_agg_fast<<<(N + 3) / 4, 256, 0, stream>>>(nodes, neigh_idx, u2e, u2e_h,
                                                exb, start, out, N);
}